// Round 14
// baseline (240.197 us; speedup 1.0000x reference)
//
#include <hip/hip_runtime.h>

#define N_MET 100000
#define N_RXN 50000
#define E_SUB 2000000
#define E_ALL 4000000
#define MSG_DIM 16
#define HIDDEN 32

// dxdt-side binning: buckets of 256 metabolites, 16384-edge tiles,
// SLOT-RESERVED global layout: bucket q owns pc[q*SLOT_A .. +gcntA[q]).
#define NBKT_A 391            // ceil(100000/256)
#define NB_ALL 245            // ceil(4000000/16384)
#define TILE_A 16384
#define SLOT_A 12288          // per-bucket capacity (mean 10230, sigma 101 -> 20-sigma safe)
// v-side binning: buckets of 64 reactions, 8192-edge tiles, SLOT-RESERVED
// global layout: bucket q owns pxs[q*SLOT_S .. q*SLOT_S+gcntS[q]).
#define NBKT_S 782            // ceil(50000/64)
#define NB_SUB 245            // ceil(2000000/8192)
#define TILE_S 8192
#define SLOT_S 4096           // per-bucket capacity (mean 2557, sigma 51 -> 29-sigma safe)
#define CHUNK_M 3072          // bucket_msg chunk: covers mean+10sigma in ONE chunk

// HW model (R1-R26): scattered GLOBAL atomics = ~19-20 G ops/s wall.
// R13/R17: per-edge latency-chain designs land ~450us, VALU<9%. R14/R15:
// in-LDS counting sort + atomic-free register reduce = proven structure.
// R20: per-block device-scope fences poison. R21/R23: fragmentation cost
// conserved; slot reservation = contiguous-both-sides, no histogram.
// R25: chunk-count model dead — marginal chunk cost ~3us; bucket_msg time
// lives in the reduce loop. R26 (this round): the 4-pair reduce walls at
// max(rl) per pair (rl~Poisson(40), wave max ~52x4 vs balanced 160 =>
// ~25-30% waste). Fix: balanced segment walk — half-wave k owns exactly
// clen/16 edges of the SORTED chunk, register-accumulates per run, one
// fire-and-forget ds_add per run boundary (~10/half-wave). Plus exp2-fold:
// pre-scale W1 by 2*log2e so tanh = 1-2*rcp(exp2(z')+1), -2 mul/tanh.

#define TWO_LOG2E 2.8853900817779268f   // 2/ln(2)

__device__ __forceinline__ float fast_tanh2(float z2) {
    // z2 = 2*log2e*z  =>  tanh(z) = 1 - 2/(2^z2 + 1); saturates at +-inf.
    const float e = exp2f(z2);
    return 1.0f - 2.0f * __builtin_amdgcn_rcpf(e + 1.0f);
}

__device__ __forceinline__ float fast_tanh(float x) {
    // tanh(x) = 1 - 2/(e^{2x}+1); for the epilogue rate MLP.
    const float e = __expf(2.0f * x);
    return 1.0f - 2.0f * __builtin_amdgcn_rcpf(e + 1.0f);
}

__global__ __launch_bounds__(1024) void zero_cnt_kernel(
    int* __restrict__ gs, int* __restrict__ ga)
{
    const int t = threadIdx.x;
    for (int i = t; i < NBKT_S; i += 1024) gs[i] = 0;
    for (int i = t; i < NBKT_A; i += 1024) ga[i] = 0;
}

// ---- Phase 1: v (slot-reserved, no histogram) -------------------------------

// counting-sort scatter (8192-edge tile, 8 consecutive edges/thread with
// int4/float4 loads): rank via LDS atomic, single-wave scan, LDS sort,
// one global atomicAdd per bucket reserves the run's slot offset, then
// runs copy out as coalesced bursts (quarter-wave per run).
// payload {x, s'} where s' carries rxn&63 in its low 6 mantissa bits.
__global__ __launch_bounds__(1024) void scatter_bin_sub_kernel(
    const float* __restrict__ x_met, const float* __restrict__ sto_sub,
    const int* __restrict__ met_sub, const int* __restrict__ rxn_sub,
    int* __restrict__ gcnt, float2* __restrict__ pxs)
{
    __shared__ float2 se[TILE_S];        // sorted payloads (64 KB)
    __shared__ int cnt[NBKT_S];
    __shared__ int loff[NBKT_S + 1];
    __shared__ int roff[NBKT_S];
    const int t = threadIdx.x, bk = blockIdx.x;
    for (int i = t; i < NBKT_S; i += 1024) cnt[i] = 0;
    __syncthreads();

    const int e0 = bk * TILE_S;
    const int rem = min(TILE_S, E_SUB - e0);
    const int tb = 8 * t;
    float2 pay[8]; int meta[8];
    if (tb + 8 <= rem) {
        const int4 r01 = ((const int4*)(rxn_sub + e0))[2 * t];
        const int4 r23 = ((const int4*)(rxn_sub + e0))[2 * t + 1];
        const int4 m01 = ((const int4*)(met_sub + e0))[2 * t];
        const int4 m23 = ((const int4*)(met_sub + e0))[2 * t + 1];
        const float4 s01 = ((const float4*)(sto_sub + e0))[2 * t];
        const float4 s23 = ((const float4*)(sto_sub + e0))[2 * t + 1];
        const int rr[8] = {r01.x, r01.y, r01.z, r01.w, r23.x, r23.y, r23.z, r23.w};
        const int mm[8] = {m01.x, m01.y, m01.z, m01.w, m23.x, m23.y, m23.z, m23.w};
        const float ss[8] = {s01.x, s01.y, s01.z, s01.w, s23.x, s23.y, s23.z, s23.w};
#pragma unroll
        for (int k = 0; k < 8; ++k) {
            const int r = rr[k];
            const float x = x_met[mm[k]];
            const int sb = (__float_as_int(ss[k]) & ~63) | (r & 63);
            pay[k] = make_float2(x, __int_as_float(sb));
            const int q = r >> 6;
            meta[k] = (atomicAdd(&cnt[q], 1) << 10) | q;   // rank 13b, q 10b
        }
    } else {
#pragma unroll
        for (int k = 0; k < 8; ++k) {
            const int e = e0 + tb + k;
            if (e < E_SUB) {
                const int r = rxn_sub[e];
                const float x = x_met[met_sub[e]];
                const int sb = (__float_as_int(sto_sub[e]) & ~63) | (r & 63);
                pay[k] = make_float2(x, __int_as_float(sb));
                const int q = r >> 6;
                meta[k] = (atomicAdd(&cnt[q], 1) << 10) | q;
            } else meta[k] = -1;
        }
    }
    __syncthreads();

    // single-wave exclusive scan of cnt[782] -> loff
    if (t < 64) {
        int carry = 0;
        for (int bb = 0; bb < NBKT_S; bb += 64) {
            const int idx = bb + t;
            const int val = (idx < NBKT_S) ? cnt[idx] : 0;
            int x = val;
#pragma unroll
            for (int off = 1; off < 64; off <<= 1) {
                const int y = __shfl_up(x, off);
                if (t >= off) x += y;
            }
            if (idx < NBKT_S) loff[idx] = carry + x - val;
            carry += __shfl(x, 63);
        }
        if (t == 0) loff[NBKT_S] = carry;
    }
    __syncthreads();

    // scatter into sorted LDS order; meanwhile reserve global slot space
#pragma unroll
    for (int k = 0; k < 8; ++k) {
        if (meta[k] >= 0)
            se[loff[meta[k] & 1023] + (meta[k] >> 10)] = pay[k];
    }
    for (int q = t; q < NBKT_S; q += 1024) {
        const int len = loff[q + 1] - loff[q];
        roff[q] = len ? atomicAdd(&gcnt[q], len) : 0;
    }
    __syncthreads();

    // copy-out: quarter-wave (16 lanes) per run, coalesced bursts
    const int qw = t >> 4, ql = t & 15;
    for (int q = qw; q < NBKT_S; q += 64) {
        const int s = loff[q], len = loff[q + 1] - s;
        float2* d = pxs + (size_t)q * SLOT_S + roff[q];
        for (int i = ql; i < len; i += 16)
            d[i] = se[s + i];
    }
}

// one block (512 thr, 8 waves) per bucket of 64 reactions. Single-chunk,
// single-round (38.4KB LDS, 4 blk/CU). Chunk: counting-sort by rxn in LDS,
// then BALANCED SEGMENT WALK: half-wave k owns exactly clen/16 edges of
// the sorted chunk; all 32 lanes (lane = hidden dim j, weights pre-scaled
// by 2*log2e in registers) process the same edge; register accumulation
// per run, one fire-and-forget ds_add per run boundary into zeroed sth.
// Epilogue: W2m matmul (linearity of segment_sum) + rate MLP.
__global__ __launch_bounds__(512, 8) void bucket_msg_kernel(
    const float2* __restrict__ pxs, const int* __restrict__ gcnt,
    const float* __restrict__ W1m, const float* __restrict__ b1m,
    const float* __restrict__ W2m, const float* __restrict__ b2m,
    const float* __restrict__ W1r, const float* __restrict__ b1r,
    const float* __restrict__ W2r, const float* __restrict__ b2r,
    float* __restrict__ v)
{
    __shared__ float2 se[CHUNK_M];           // edges (24 KB); epilogue sh aliases
    __shared__ float  sth[64 * 33];          // tanh sums [rxn][j], stride 33
    __shared__ int    cnt[64];               // per-chunk run lengths
    __shared__ int    soff[65];              // per-chunk run offsets
    __shared__ int    ccnt[64];              // total edge count per rxn
    __shared__ float  sW2m[HIDDEN * MSG_DIM];
    __shared__ float  sb2m[MSG_DIM];
    __shared__ float  sW1r[MSG_DIM * HIDDEN];
    __shared__ float  sb1r[HIDDEN];
    __shared__ float  sW2r[HIDDEN];
    __shared__ float  sb2r;
    float* const sh = (float*)se;            // h[64][17] (4.4KB), aliases dead se

    const int t = threadIdx.x;
    const int w = t >> 6, l = t & 63;
    const int half = l >> 5, j = l & 31;

    // stage weights
    for (int i = t; i < HIDDEN * MSG_DIM; i += 512) sW2m[i] = W2m[i];
    for (int i = t; i < MSG_DIM * HIDDEN; i += 512) sW1r[i] = W1r[i];
    if (t < MSG_DIM) sb2m[t] = b2m[t];
    if (t < HIDDEN) sb1r[t] = b1r[t];
    if (t >= 64 && t < 64 + HIDDEN) sW2r[t - 64] = W2r[t - 64];
    if (t == 128) sb2r = b2r[0];
    if (t < 64) ccnt[t] = 0;
    for (int i = t; i < 64 * 33; i += 512) sth[i] = 0.0f;

    // per-lane W1 column, pre-scaled by 2*log2e (exp2-folded tanh)
    const float w1x2 = W1m[j] * TWO_LOG2E;
    const float w1y2 = W1m[HIDDEN + j] * TWO_LOG2E;
    const float w1b2 = b1m[j] * TWO_LOG2E;

    const int b = blockIdx.x;
    const int beg = b * SLOT_S;
    const int end = beg + gcnt[b];

    for (int cb = beg; cb < end; cb += CHUNK_M) {
        const int clen = min(end - cb, CHUNK_M);
        if (t < 64) cnt[t] = 0;
        __syncthreads();

        // load + rank (counting-sort pass 1): 6 slots/thread covers 3072
        float2 pay[6];
        int meta[6];
#pragma unroll
        for (int k = 0; k < 6; ++k) {
            const int sl = t + (k << 9);
            if (sl < clen) {
                const float2 pv = pxs[cb + sl];
                const int r = __float_as_int(pv.y) & 63;
                meta[k] = (atomicAdd(&cnt[r], 1) << 6) | r;
                pay[k] = pv;
            } else meta[k] = -1;
        }
        __syncthreads();

        // scan 64 bins (wave 0)
        if (t < 64) {
            const int orig = cnt[t];
            int x = orig;
#pragma unroll
            for (int off = 1; off < 64; off <<= 1) {
                const int y = __shfl_up(x, off);
                if (t >= off) x += y;
            }
            soff[t] = x - orig;           // exclusive
            if (t == 63) soff[64] = x;    // chunk total
            ccnt[t] += orig;
        }
        __syncthreads();

        // scatter into sorted order (pass 2)
#pragma unroll
        for (int k = 0; k < 6; ++k) {
            if (meta[k] >= 0)
                se[soff[meta[k] & 63] + (meta[k] >> 6)] = pay[k];
        }
        __syncthreads();

        // BALANCED WALK: half-wave k16 owns [clen*k16/16, clen*(k16+1)/16)
        {
            const int k16 = (w << 1) + half;
            const int s0 = (clen * k16) >> 4;
            const int s1 = (clen * (k16 + 1)) >> 4;
            int cur = -1;
            float a = 0.0f;
#pragma unroll 2
            for (int i = s0; i < s1; ++i) {
                const float2 ev = se[i];
                const int r = __float_as_int(ev.y) & 63;
                if (r != cur) {
                    if (cur >= 0) atomicAdd(&sth[cur * 33 + j], a);
                    cur = r; a = 0.0f;
                }
                a += fast_tanh2(fmaf(ev.x, w1x2, fmaf(ev.y, w1y2, w1b2)));
            }
            if (cur >= 0) atomicAdd(&sth[cur * 33 + j], a);
        }
        __syncthreads();   // protect cnt/soff/se before next chunk
    }

    // stage A: h[r][d] = cnt[r]*b2m[d] + sum_j sth[r][j] * W2m[j][d]
    // (sh aliases se — se is dead after the main loop)
    {
        const int r = t & 63, g = (t >> 6) << 1;
        const float cntf = (float)ccnt[r];
        float h0 = cntf * sb2m[g + 0], h1 = cntf * sb2m[g + 1];
#pragma unroll 8
        for (int jj = 0; jj < HIDDEN; ++jj) {
            const float ts = sth[r * 33 + jj];
            h0 = fmaf(ts, sW2m[jj * MSG_DIM + g + 0], h0);
            h1 = fmaf(ts, sW2m[jj * MSG_DIM + g + 1], h1);
        }
        sh[r * 17 + g + 0] = h0;
        sh[r * 17 + g + 1] = h1;
    }
    __syncthreads();

    // stage B: rate MLP; thread t (<64) owns reaction b*64+t
    if (t < 64) {
        const int r = b * 64 + t;
        if (r < N_RXN) {
            float h[MSG_DIM];
#pragma unroll
            for (int d = 0; d < MSG_DIM; ++d) h[d] = sh[t * 17 + d];
            float acc2 = sb2r;
#pragma unroll 2
            for (int jj = 0; jj < HIDDEN; ++jj) {
                float z = sb1r[jj];
#pragma unroll
                for (int d = 0; d < MSG_DIM; ++d)
                    z = fmaf(h[d], sW1r[d * HIDDEN + jj], z);
                acc2 = fmaf(fast_tanh(z), sW2r[jj], acc2);
            }
            v[r] = fmaxf(acc2, 0.0f) + log1pf(expf(-fabsf(acc2)));
        }
    }
}

// ---- Phase 2: dxdt (slot-reserved, no histogram) ----------------------------

// counting-sort scatter (16384-edge tile, two-pass): pass A ranks on met
// (int4 loads, meta = (rank<<17)|met); pass B re-reads rxn/sto (L2-hot) as
// int4/float4 and writes the packed payload into sorted LDS. One global
// atomicAdd per bucket reserves slot space; runs copy out as bursts.
// Payload c packs met&255 into its low 8 mantissa bits (rel err ~3e-5).
__global__ __launch_bounds__(1024) void scatter_bin_kernel(
    const float* __restrict__ sto_all, const float* __restrict__ v,
    const int* __restrict__ met_all, const int* __restrict__ rxn_all,
    int* __restrict__ gcntA, float* __restrict__ pc)
{
    __shared__ float sp[TILE_A];         // sorted payloads (64 KB)
    __shared__ int cnt[NBKT_A];
    __shared__ int loff[NBKT_A + 1];
    __shared__ int roff[NBKT_A];
    const int t = threadIdx.x, bk = blockIdx.x;
    for (int i = t; i < NBKT_A; i += 1024) cnt[i] = 0;
    __syncthreads();

    const int e0 = bk * TILE_A;
    const int rem = min(TILE_A, E_ALL - e0);
    const int tb = 16 * t;
    int meta[16];
    const bool full = (tb + 16 <= rem);
    if (full) {
#pragma unroll
        for (int kk = 0; kk < 4; ++kk) {
            const int4 m = ((const int4*)(met_all + e0))[4 * t + kk];
            meta[4 * kk + 0] = (atomicAdd(&cnt[m.x >> 8], 1) << 17) | m.x;
            meta[4 * kk + 1] = (atomicAdd(&cnt[m.y >> 8], 1) << 17) | m.y;
            meta[4 * kk + 2] = (atomicAdd(&cnt[m.z >> 8], 1) << 17) | m.z;
            meta[4 * kk + 3] = (atomicAdd(&cnt[m.w >> 8], 1) << 17) | m.w;
        }
    } else {
#pragma unroll
        for (int k = 0; k < 16; ++k) {
            const int e = e0 + tb + k;
            if (e < E_ALL) {
                const int m = met_all[e];
                meta[k] = (atomicAdd(&cnt[m >> 8], 1) << 17) | m;
            } else meta[k] = -1;
        }
    }
    __syncthreads();

    // single-wave exclusive scan of cnt[391] -> loff
    if (t < 64) {
        int carry = 0;
        for (int bb = 0; bb < NBKT_A; bb += 64) {
            const int idx = bb + t;
            const int val = (idx < NBKT_A) ? cnt[idx] : 0;
            int x = val;
#pragma unroll
            for (int off = 1; off < 64; off <<= 1) {
                const int y = __shfl_up(x, off);
                if (t >= off) x += y;
            }
            if (idx < NBKT_A) loff[idx] = carry + x - val;
            carry += __shfl(x, 63);
        }
        if (t == 0) loff[NBKT_A] = carry;
    }
    __syncthreads();

    // reserve slot space (one global atomicAdd per non-empty bucket)
    for (int q = t; q < NBKT_A; q += 1024) {
        const int len = loff[q + 1] - loff[q];
        roff[q] = len ? atomicAdd(&gcntA[q], len) : 0;
    }

    // pass B: payloads from rxn/sto (L2-hot second read), sorted LDS write
    if (full) {
#pragma unroll
        for (int kk = 0; kk < 4; ++kk) {
            const int4 r = ((const int4*)(rxn_all + e0))[4 * t + kk];
            const float4 s = ((const float4*)(sto_all + e0))[4 * t + kk];
            const int rr[4] = {r.x, r.y, r.z, r.w};
            const float ss[4] = {s.x, s.y, s.z, s.w};
#pragma unroll
            for (int u = 0; u < 4; ++u) {
                const int mt = meta[4 * kk + u];
                const int m = mt & 0x1FFFF;
                const float c = ss[u] * v[rr[u]];
                const int cb = (__float_as_int(c) & ~255) | (m & 255);
                sp[loff[m >> 8] + (mt >> 17)] = __int_as_float(cb);
            }
        }
    } else {
#pragma unroll
        for (int k = 0; k < 16; ++k) {
            const int e = e0 + tb + k;
            if (e < E_ALL) {
                const int mt = meta[k];
                const int m = mt & 0x1FFFF;
                const float c = sto_all[e] * v[rxn_all[e]];
                const int cb = (__float_as_int(c) & ~255) | (m & 255);
                sp[loff[m >> 8] + (mt >> 17)] = __int_as_float(cb);
            }
        }
    }
    __syncthreads();

    // copy-out: quarter-wave (16 lanes) per run, coalesced bursts
    const int qw = t >> 4, ql = t & 15;
    for (int q = qw; q < NBKT_A; q += 64) {
        const int s = loff[q], len = loff[q + 1] - s;
        float* d = pc + (size_t)q * SLOT_A + roff[q];
        for (int i = ql; i < len; i += 16)
            d[i] = sp[s + i];
    }
}

// block = bucket q (391 blocks): ONE dense slot read, float4 + 4-deep ILP
// LDS atomics, then 256 threads write dxdt. No descriptors, no segments.
__global__ __launch_bounds__(512) void bucket_accum_kernel(
    const float* __restrict__ pc, const int* __restrict__ gcntA,
    float* __restrict__ dxdt)
{
    __shared__ float acc[256];
    const int q = blockIdx.x, t = threadIdx.x;
    if (t < 256) acc[t] = 0.0f;
    __syncthreads();
    const float* s = pc + (size_t)q * SLOT_A;   // 16B-aligned (SLOT_A%4==0)
    const int n = gcntA[q];
    const int n4 = n & ~3;
    for (int i = 4 * t; i < n4; i += 2048) {
        const float4 pv = *(const float4*)(s + i);
        atomicAdd(&acc[__float_as_int(pv.x) & 255], pv.x);
        atomicAdd(&acc[__float_as_int(pv.y) & 255], pv.y);
        atomicAdd(&acc[__float_as_int(pv.z) & 255], pv.z);
        atomicAdd(&acc[__float_as_int(pv.w) & 255], pv.w);
    }
    for (int i = n4 + t; i < n; i += 512) {
        const float pv = s[i];
        atomicAdd(&acc[__float_as_int(pv) & 255], pv);
    }
    __syncthreads();
    if (t < 256) {
        const int met = q * 256 + t;
        if (met < N_MET) dxdt[met] = acc[t];
    }
}

extern "C" void kernel_launch(void* const* d_in, const int* in_sizes, int n_in,
                              void* d_out, int out_size, void* d_ws, size_t ws_size,
                              hipStream_t stream) {
    const float* x_met   = (const float*)d_in[0];
    const float* sto_sub = (const float*)d_in[1];
    const float* sto_all = (const float*)d_in[2];
    const float* W1m     = (const float*)d_in[3];
    const float* b1m     = (const float*)d_in[4];
    const float* W2m     = (const float*)d_in[5];
    const float* b2m     = (const float*)d_in[6];
    const float* W1r     = (const float*)d_in[7];
    const float* b1r     = (const float*)d_in[8];
    const float* W2r     = (const float*)d_in[9];
    const float* b2r     = (const float*)d_in[10];
    const int*   met_sub = (const int*)d_in[11];
    const int*   rxn_sub = (const int*)d_in[12];
    const int*   met_all = (const int*)d_in[13];
    const int*   rxn_all = (const int*)d_in[14];

    float* dxdt = (float*)d_out;             // [N_MET]
    float* v    = dxdt + N_MET;              // [N_RXN]

    // workspace: gcntS + gcntA + payload union. pxs (25.6 MB slotted, dead
    // after bucket_msg) aliases pc (19.2 MB slotted, written strictly later
    // in stream order).
    char* ws = (char*)d_ws;
    int* gcntS  = (int*)ws;  ws += ((sizeof(int) * NBKT_S + 15) / 16) * 16;
    int* gcntA  = (int*)ws;  ws += ((sizeof(int) * NBKT_A + 15) / 16) * 16;
    char* P = ws;                          // payload union, 25.6 MB
    float2* pxs = (float2*)P;              // [NBKT_S * SLOT_S]  25.6 MB
    float*  pc  = (float*)P;               // [NBKT_A * SLOT_A]  19.2 MB

    // zero both phases' slot counters in one tiny launch
    zero_cnt_kernel<<<1, 1024, 0, stream>>>(gcntS, gcntA);

    // phase 1: v (slot-reserved; no hist/scan launches)
    scatter_bin_sub_kernel<<<NB_SUB, 1024, 0, stream>>>(
        x_met, sto_sub, met_sub, rxn_sub, gcntS, pxs);
    bucket_msg_kernel<<<NBKT_S, 512, 0, stream>>>(
        pxs, gcntS, W1m, b1m, W2m, b2m, W1r, b1r, W2r, b2r, v);

    // phase 2: dxdt (slot-reserved)
    scatter_bin_kernel<<<NB_ALL, 1024, 0, stream>>>(
        sto_all, v, met_all, rxn_all, gcntA, pc);
    bucket_accum_kernel<<<NBKT_A, 512, 0, stream>>>(pc, gcntA, dxdt);
}

// Round 15
// 236.175 us; speedup vs baseline: 1.0170x; 1.0170x over previous
//
#include <hip/hip_runtime.h>

#define N_MET 100000
#define N_RXN 50000
#define E_SUB 2000000
#define E_ALL 4000000
#define MSG_DIM 16
#define HIDDEN 32

// dxdt-side binning: buckets of 256 metabolites, 16384-edge tiles,
// SLOT-RESERVED global layout: bucket q owns pc[q*SLOT_A .. +gcntA[q]).
#define NBKT_A 391            // ceil(100000/256)
#define NB_ALL 245            // ceil(4000000/16384)
#define TILE_A 16384
#define SLOT_A 12288          // per-bucket capacity (mean 10230, sigma 101 -> 20-sigma safe)
// v-side binning: buckets of 64 reactions, 8192-edge tiles, SLOT-RESERVED
// global layout: bucket q owns pxs[q*SLOT_S .. q*SLOT_S+gcntS[q]).
#define NBKT_S 782            // ceil(50000/64)
#define NB_SUB 245            // ceil(2000000/8192)
#define TILE_S 8192
#define SLOT_S 4096           // per-bucket capacity (mean 2557, sigma 51 -> 29-sigma safe)
#define CHUNK_M 3072          // bucket_msg chunk: covers mean+10sigma in ONE chunk

// HW model (R1-R27): scattered GLOBAL atomics = ~19-20 G ops/s wall.
// R13/R17: per-edge latency-chain designs land ~450us, VALU<9%. R14/R15:
// in-LDS counting sort + atomic-free register reduce = proven structure.
// R20: per-block device-scope fences poison. R21/R23: fragmentation cost
// conserved; slot reservation = contiguous-both-sides, no histogram.
// R25: chunk-count model dead — marginal chunk ~3us; time is in the reduce
// loop. R26: balanced-walk REGRESSED (55 vs 45) — serial accumulator +
// per-edge branch halves wave edge-throughput; R27: in this latency-
// dominated reduce, accumulator ILP x edges/iter beats work balance.
// R15 (this round): R13 pair-reduce + ILP-4 chains + exp2-folded tanh
// (W1 pre-scaled by 2*log2e; -2 ops per tanh of 64M).

#define TWO_LOG2E 2.8853900817779268f   // 2/ln(2)

__device__ __forceinline__ float fast_tanh2(float z2) {
    // z2 = (2*log2e)*z  =>  tanh(z) = 1 - 2/(2^z2 + 1); saturates at +-inf.
    const float e = exp2f(z2);
    return 1.0f - 2.0f * __builtin_amdgcn_rcpf(e + 1.0f);
}

__device__ __forceinline__ float fast_tanh(float x) {
    // tanh(x) = 1 - 2/(e^{2x}+1); for the epilogue rate MLP.
    const float e = __expf(2.0f * x);
    return 1.0f - 2.0f * __builtin_amdgcn_rcpf(e + 1.0f);
}

__global__ __launch_bounds__(1024) void zero_cnt_kernel(
    int* __restrict__ gs, int* __restrict__ ga)
{
    const int t = threadIdx.x;
    for (int i = t; i < NBKT_S; i += 1024) gs[i] = 0;
    for (int i = t; i < NBKT_A; i += 1024) ga[i] = 0;
}

// ---- Phase 1: v (slot-reserved, no histogram) -------------------------------

// counting-sort scatter (8192-edge tile, 8 consecutive edges/thread with
// int4/float4 loads): rank via LDS atomic, single-wave scan, LDS sort,
// one global atomicAdd per bucket reserves the run's slot offset, then
// runs copy out as coalesced bursts (quarter-wave per run).
// payload {x, s'} where s' carries rxn&63 in its low 6 mantissa bits.
__global__ __launch_bounds__(1024) void scatter_bin_sub_kernel(
    const float* __restrict__ x_met, const float* __restrict__ sto_sub,
    const int* __restrict__ met_sub, const int* __restrict__ rxn_sub,
    int* __restrict__ gcnt, float2* __restrict__ pxs)
{
    __shared__ float2 se[TILE_S];        // sorted payloads (64 KB)
    __shared__ int cnt[NBKT_S];
    __shared__ int loff[NBKT_S + 1];
    __shared__ int roff[NBKT_S];
    const int t = threadIdx.x, bk = blockIdx.x;
    for (int i = t; i < NBKT_S; i += 1024) cnt[i] = 0;
    __syncthreads();

    const int e0 = bk * TILE_S;
    const int rem = min(TILE_S, E_SUB - e0);
    const int tb = 8 * t;
    float2 pay[8]; int meta[8];
    if (tb + 8 <= rem) {
        const int4 r01 = ((const int4*)(rxn_sub + e0))[2 * t];
        const int4 r23 = ((const int4*)(rxn_sub + e0))[2 * t + 1];
        const int4 m01 = ((const int4*)(met_sub + e0))[2 * t];
        const int4 m23 = ((const int4*)(met_sub + e0))[2 * t + 1];
        const float4 s01 = ((const float4*)(sto_sub + e0))[2 * t];
        const float4 s23 = ((const float4*)(sto_sub + e0))[2 * t + 1];
        const int rr[8] = {r01.x, r01.y, r01.z, r01.w, r23.x, r23.y, r23.z, r23.w};
        const int mm[8] = {m01.x, m01.y, m01.z, m01.w, m23.x, m23.y, m23.z, m23.w};
        const float ss[8] = {s01.x, s01.y, s01.z, s01.w, s23.x, s23.y, s23.z, s23.w};
#pragma unroll
        for (int k = 0; k < 8; ++k) {
            const int r = rr[k];
            const float x = x_met[mm[k]];
            const int sb = (__float_as_int(ss[k]) & ~63) | (r & 63);
            pay[k] = make_float2(x, __int_as_float(sb));
            const int q = r >> 6;
            meta[k] = (atomicAdd(&cnt[q], 1) << 10) | q;   // rank 13b, q 10b
        }
    } else {
#pragma unroll
        for (int k = 0; k < 8; ++k) {
            const int e = e0 + tb + k;
            if (e < E_SUB) {
                const int r = rxn_sub[e];
                const float x = x_met[met_sub[e]];
                const int sb = (__float_as_int(sto_sub[e]) & ~63) | (r & 63);
                pay[k] = make_float2(x, __int_as_float(sb));
                const int q = r >> 6;
                meta[k] = (atomicAdd(&cnt[q], 1) << 10) | q;
            } else meta[k] = -1;
        }
    }
    __syncthreads();

    // single-wave exclusive scan of cnt[782] -> loff
    if (t < 64) {
        int carry = 0;
        for (int bb = 0; bb < NBKT_S; bb += 64) {
            const int idx = bb + t;
            const int val = (idx < NBKT_S) ? cnt[idx] : 0;
            int x = val;
#pragma unroll
            for (int off = 1; off < 64; off <<= 1) {
                const int y = __shfl_up(x, off);
                if (t >= off) x += y;
            }
            if (idx < NBKT_S) loff[idx] = carry + x - val;
            carry += __shfl(x, 63);
        }
        if (t == 0) loff[NBKT_S] = carry;
    }
    __syncthreads();

    // scatter into sorted LDS order; meanwhile reserve global slot space
#pragma unroll
    for (int k = 0; k < 8; ++k) {
        if (meta[k] >= 0)
            se[loff[meta[k] & 1023] + (meta[k] >> 10)] = pay[k];
    }
    for (int q = t; q < NBKT_S; q += 1024) {
        const int len = loff[q + 1] - loff[q];
        roff[q] = len ? atomicAdd(&gcnt[q], len) : 0;
    }
    __syncthreads();

    // copy-out: quarter-wave (16 lanes) per run, coalesced bursts
    const int qw = t >> 4, ql = t & 15;
    for (int q = qw; q < NBKT_S; q += 64) {
        const int s = loff[q], len = loff[q + 1] - s;
        float2* d = pxs + (size_t)q * SLOT_S + roff[q];
        for (int i = ql; i < len; i += 16)
            d[i] = se[s + i];
    }
}

// one block (512 thr, 8 waves) per bucket of 64 reactions. Single-chunk,
// single-round (38.4KB LDS, 4 blk/CU). Chunk: counting-sort by rxn in LDS
// (1 rank-atomic/edge), then wave w reduces rxns w*8..w*8+7 as 4 pairs:
// lane half = rxn of pair, j = lane&31 = hidden dim (W1 pre-scaled by
// 2*log2e in registers); broadcast ds_read, ILP-4 register tanh chains,
// one ds_write per (r,j). Epilogue: W2m matmul (linearity) + rate MLP.
__global__ __launch_bounds__(512, 8) void bucket_msg_kernel(
    const float2* __restrict__ pxs, const int* __restrict__ gcnt,
    const float* __restrict__ W1m, const float* __restrict__ b1m,
    const float* __restrict__ W2m, const float* __restrict__ b2m,
    const float* __restrict__ W1r, const float* __restrict__ b1r,
    const float* __restrict__ W2r, const float* __restrict__ b2r,
    float* __restrict__ v)
{
    __shared__ float2 se[CHUNK_M];           // edges (24 KB); epilogue sh aliases
    __shared__ float  sth[64 * 33];          // tanh sums [rxn][j], stride 33
    __shared__ int    cnt[64];               // per-chunk run lengths
    __shared__ int    soff[65];              // per-chunk run offsets
    __shared__ int    ccnt[64];              // total edge count per rxn
    __shared__ float  sW2m[HIDDEN * MSG_DIM];
    __shared__ float  sb2m[MSG_DIM];
    __shared__ float  sW1r[MSG_DIM * HIDDEN];
    __shared__ float  sb1r[HIDDEN];
    __shared__ float  sW2r[HIDDEN];
    __shared__ float  sb2r;
    float* const sh = (float*)se;            // h[64][17] (4.4KB), aliases dead se

    const int t = threadIdx.x;
    const int w = t >> 6, l = t & 63;
    const int half = l >> 5, j = l & 31;

    // stage weights
    for (int i = t; i < HIDDEN * MSG_DIM; i += 512) sW2m[i] = W2m[i];
    for (int i = t; i < MSG_DIM * HIDDEN; i += 512) sW1r[i] = W1r[i];
    if (t < MSG_DIM) sb2m[t] = b2m[t];
    if (t < HIDDEN) sb1r[t] = b1r[t];
    if (t >= 64 && t < 64 + HIDDEN) sW2r[t - 64] = W2r[t - 64];
    if (t == 128) sb2r = b2r[0];
    if (t < 64) ccnt[t] = 0;

    // per-lane W1 column, pre-scaled by 2*log2e (exp2-folded tanh)
    const float w1x2 = W1m[j] * TWO_LOG2E;
    const float w1y2 = W1m[HIDDEN + j] * TWO_LOG2E;
    const float w1b2 = b1m[j] * TWO_LOG2E;

    const int b = blockIdx.x;
    const int beg = b * SLOT_S;
    const int end = beg + gcnt[b];

    float acc[4] = {0.0f, 0.0f, 0.0f, 0.0f};   // per (pair) tanh sums

    for (int cb = beg; cb < end; cb += CHUNK_M) {
        const int clen = min(end - cb, CHUNK_M);
        if (t < 64) cnt[t] = 0;
        __syncthreads();

        // load + rank (counting-sort pass 1): 6 slots/thread covers 3072
        float2 pay[6];
        int meta[6];
#pragma unroll
        for (int k = 0; k < 6; ++k) {
            const int sl = t + (k << 9);
            if (sl < clen) {
                const float2 pv = pxs[cb + sl];
                const int r = __float_as_int(pv.y) & 63;
                meta[k] = (atomicAdd(&cnt[r], 1) << 6) | r;
                pay[k] = pv;
            } else meta[k] = -1;
        }
        __syncthreads();

        // scan 64 bins (wave 0)
        if (t < 64) {
            const int orig = cnt[t];
            int x = orig;
#pragma unroll
            for (int off = 1; off < 64; off <<= 1) {
                const int y = __shfl_up(x, off);
                if (t >= off) x += y;
            }
            soff[t] = x - orig;           // exclusive
            if (t == 63) soff[64] = x;    // chunk total
            ccnt[t] += orig;
        }
        __syncthreads();

        // scatter into sorted order (pass 2)
#pragma unroll
        for (int k = 0; k < 6; ++k) {
            if (meta[k] >= 0)
                se[soff[meta[k] & 63] + (meta[k] >> 6)] = pay[k];
        }
        __syncthreads();

        // atomic-free reduce: wave w owns rxns w*8..w*8+7 as 4 pairs,
        // ILP-4 accumulator chains (two quarter-rate trans ops per tanh).
#pragma unroll
        for (int p = 0; p < 4; ++p) {
            const int q = (w << 3) + (p << 1) + half;
            const int rb = soff[q];
            const int rl = soff[q + 1] - rb;
            float a0 = 0.0f, a1 = 0.0f, a2 = 0.0f, a3 = 0.0f;
            int i = 0;
            for (; i + 4 <= rl; i += 4) {
                const float2 e0 = se[rb + i];
                const float2 e1 = se[rb + i + 1];
                const float2 e2 = se[rb + i + 2];
                const float2 e3 = se[rb + i + 3];
                a0 += fast_tanh2(fmaf(e0.x, w1x2, fmaf(e0.y, w1y2, w1b2)));
                a1 += fast_tanh2(fmaf(e1.x, w1x2, fmaf(e1.y, w1y2, w1b2)));
                a2 += fast_tanh2(fmaf(e2.x, w1x2, fmaf(e2.y, w1y2, w1b2)));
                a3 += fast_tanh2(fmaf(e3.x, w1x2, fmaf(e3.y, w1y2, w1b2)));
            }
            for (; i < rl; ++i) {
                const float2 e0 = se[rb + i];
                a0 += fast_tanh2(fmaf(e0.x, w1x2, fmaf(e0.y, w1y2, w1b2)));
            }
            acc[p] += (a0 + a1) + (a2 + a3);
        }
        __syncthreads();   // protect cnt/soff/se before next chunk
    }

    // write tanh sums: unique owner per (rxn, j) — plain stores, stride 33
#pragma unroll
    for (int p = 0; p < 4; ++p) {
        const int q = (w << 3) + (p << 1) + half;
        sth[q * 33 + j] = acc[p];
    }
    __syncthreads();

    // stage A: h[r][d] = cnt[r]*b2m[d] + sum_j sth[r][j] * W2m[j][d]
    // (sh aliases se — se is dead after the main loop)
    {
        const int r = t & 63, g = (t >> 6) << 1;
        const float cntf = (float)ccnt[r];
        float h0 = cntf * sb2m[g + 0], h1 = cntf * sb2m[g + 1];
#pragma unroll 8
        for (int jj = 0; jj < HIDDEN; ++jj) {
            const float ts = sth[r * 33 + jj];
            h0 = fmaf(ts, sW2m[jj * MSG_DIM + g + 0], h0);
            h1 = fmaf(ts, sW2m[jj * MSG_DIM + g + 1], h1);
        }
        sh[r * 17 + g + 0] = h0;
        sh[r * 17 + g + 1] = h1;
    }
    __syncthreads();

    // stage B: rate MLP; thread t (<64) owns reaction b*64+t
    if (t < 64) {
        const int r = b * 64 + t;
        if (r < N_RXN) {
            float h[MSG_DIM];
#pragma unroll
            for (int d = 0; d < MSG_DIM; ++d) h[d] = sh[t * 17 + d];
            float acc2 = sb2r;
#pragma unroll 2
            for (int jj = 0; jj < HIDDEN; ++jj) {
                float z = sb1r[jj];
#pragma unroll
                for (int d = 0; d < MSG_DIM; ++d)
                    z = fmaf(h[d], sW1r[d * HIDDEN + jj], z);
                acc2 = fmaf(fast_tanh(z), sW2r[jj], acc2);
            }
            v[r] = fmaxf(acc2, 0.0f) + log1pf(expf(-fabsf(acc2)));
        }
    }
}

// ---- Phase 2: dxdt (slot-reserved, no histogram) ----------------------------

// counting-sort scatter (16384-edge tile, two-pass): pass A ranks on met
// (int4 loads, meta = (rank<<17)|met); pass B re-reads rxn/sto (L2-hot) as
// int4/float4 and writes the packed payload into sorted LDS. One global
// atomicAdd per bucket reserves slot space; runs copy out as bursts.
// Payload c packs met&255 into its low 8 mantissa bits (rel err ~3e-5).
__global__ __launch_bounds__(1024) void scatter_bin_kernel(
    const float* __restrict__ sto_all, const float* __restrict__ v,
    const int* __restrict__ met_all, const int* __restrict__ rxn_all,
    int* __restrict__ gcntA, float* __restrict__ pc)
{
    __shared__ float sp[TILE_A];         // sorted payloads (64 KB)
    __shared__ int cnt[NBKT_A];
    __shared__ int loff[NBKT_A + 1];
    __shared__ int roff[NBKT_A];
    const int t = threadIdx.x, bk = blockIdx.x;
    for (int i = t; i < NBKT_A; i += 1024) cnt[i] = 0;
    __syncthreads();

    const int e0 = bk * TILE_A;
    const int rem = min(TILE_A, E_ALL - e0);
    const int tb = 16 * t;
    int meta[16];
    const bool full = (tb + 16 <= rem);
    if (full) {
#pragma unroll
        for (int kk = 0; kk < 4; ++kk) {
            const int4 m = ((const int4*)(met_all + e0))[4 * t + kk];
            meta[4 * kk + 0] = (atomicAdd(&cnt[m.x >> 8], 1) << 17) | m.x;
            meta[4 * kk + 1] = (atomicAdd(&cnt[m.y >> 8], 1) << 17) | m.y;
            meta[4 * kk + 2] = (atomicAdd(&cnt[m.z >> 8], 1) << 17) | m.z;
            meta[4 * kk + 3] = (atomicAdd(&cnt[m.w >> 8], 1) << 17) | m.w;
        }
    } else {
#pragma unroll
        for (int k = 0; k < 16; ++k) {
            const int e = e0 + tb + k;
            if (e < E_ALL) {
                const int m = met_all[e];
                meta[k] = (atomicAdd(&cnt[m >> 8], 1) << 17) | m;
            } else meta[k] = -1;
        }
    }
    __syncthreads();

    // single-wave exclusive scan of cnt[391] -> loff
    if (t < 64) {
        int carry = 0;
        for (int bb = 0; bb < NBKT_A; bb += 64) {
            const int idx = bb + t;
            const int val = (idx < NBKT_A) ? cnt[idx] : 0;
            int x = val;
#pragma unroll
            for (int off = 1; off < 64; off <<= 1) {
                const int y = __shfl_up(x, off);
                if (t >= off) x += y;
            }
            if (idx < NBKT_A) loff[idx] = carry + x - val;
            carry += __shfl(x, 63);
        }
        if (t == 0) loff[NBKT_A] = carry;
    }
    __syncthreads();

    // reserve slot space (one global atomicAdd per non-empty bucket)
    for (int q = t; q < NBKT_A; q += 1024) {
        const int len = loff[q + 1] - loff[q];
        roff[q] = len ? atomicAdd(&gcntA[q], len) : 0;
    }

    // pass B: payloads from rxn/sto (L2-hot second read), sorted LDS write
    if (full) {
#pragma unroll
        for (int kk = 0; kk < 4; ++kk) {
            const int4 r = ((const int4*)(rxn_all + e0))[4 * t + kk];
            const float4 s = ((const float4*)(sto_all + e0))[4 * t + kk];
            const int rr[4] = {r.x, r.y, r.z, r.w};
            const float ss[4] = {s.x, s.y, s.z, s.w};
#pragma unroll
            for (int u = 0; u < 4; ++u) {
                const int mt = meta[4 * kk + u];
                const int m = mt & 0x1FFFF;
                const float c = ss[u] * v[rr[u]];
                const int cb = (__float_as_int(c) & ~255) | (m & 255);
                sp[loff[m >> 8] + (mt >> 17)] = __int_as_float(cb);
            }
        }
    } else {
#pragma unroll
        for (int k = 0; k < 16; ++k) {
            const int e = e0 + tb + k;
            if (e < E_ALL) {
                const int mt = meta[k];
                const int m = mt & 0x1FFFF;
                const float c = sto_all[e] * v[rxn_all[e]];
                const int cb = (__float_as_int(c) & ~255) | (m & 255);
                sp[loff[m >> 8] + (mt >> 17)] = __int_as_float(cb);
            }
        }
    }
    __syncthreads();

    // copy-out: quarter-wave (16 lanes) per run, coalesced bursts
    const int qw = t >> 4, ql = t & 15;
    for (int q = qw; q < NBKT_A; q += 64) {
        const int s = loff[q], len = loff[q + 1] - s;
        float* d = pc + (size_t)q * SLOT_A + roff[q];
        for (int i = ql; i < len; i += 16)
            d[i] = sp[s + i];
    }
}

// block = bucket q (391 blocks): ONE dense slot read, float4 + 4-deep ILP
// LDS atomics, then 256 threads write dxdt. No descriptors, no segments.
__global__ __launch_bounds__(512) void bucket_accum_kernel(
    const float* __restrict__ pc, const int* __restrict__ gcntA,
    float* __restrict__ dxdt)
{
    __shared__ float acc[256];
    const int q = blockIdx.x, t = threadIdx.x;
    if (t < 256) acc[t] = 0.0f;
    __syncthreads();
    const float* s = pc + (size_t)q * SLOT_A;   // 16B-aligned (SLOT_A%4==0)
    const int n = gcntA[q];
    const int n4 = n & ~3;
    for (int i = 4 * t; i < n4; i += 2048) {
        const float4 pv = *(const float4*)(s + i);
        atomicAdd(&acc[__float_as_int(pv.x) & 255], pv.x);
        atomicAdd(&acc[__float_as_int(pv.y) & 255], pv.y);
        atomicAdd(&acc[__float_as_int(pv.z) & 255], pv.z);
        atomicAdd(&acc[__float_as_int(pv.w) & 255], pv.w);
    }
    for (int i = n4 + t; i < n; i += 512) {
        const float pv = s[i];
        atomicAdd(&acc[__float_as_int(pv) & 255], pv);
    }
    __syncthreads();
    if (t < 256) {
        const int met = q * 256 + t;
        if (met < N_MET) dxdt[met] = acc[t];
    }
}

extern "C" void kernel_launch(void* const* d_in, const int* in_sizes, int n_in,
                              void* d_out, int out_size, void* d_ws, size_t ws_size,
                              hipStream_t stream) {
    const float* x_met   = (const float*)d_in[0];
    const float* sto_sub = (const float*)d_in[1];
    const float* sto_all = (const float*)d_in[2];
    const float* W1m     = (const float*)d_in[3];
    const float* b1m     = (const float*)d_in[4];
    const float* W2m     = (const float*)d_in[5];
    const float* b2m     = (const float*)d_in[6];
    const float* W1r     = (const float*)d_in[7];
    const float* b1r     = (const float*)d_in[8];
    const float* W2r     = (const float*)d_in[9];
    const float* b2r     = (const float*)d_in[10];
    const int*   met_sub = (const int*)d_in[11];
    const int*   rxn_sub = (const int*)d_in[12];
    const int*   met_all = (const int*)d_in[13];
    const int*   rxn_all = (const int*)d_in[14];

    float* dxdt = (float*)d_out;             // [N_MET]
    float* v    = dxdt + N_MET;              // [N_RXN]

    // workspace: gcntS + gcntA + payload union. pxs (25.6 MB slotted, dead
    // after bucket_msg) aliases pc (19.2 MB slotted, written strictly later
    // in stream order).
    char* ws = (char*)d_ws;
    int* gcntS  = (int*)ws;  ws += ((sizeof(int) * NBKT_S + 15) / 16) * 16;
    int* gcntA  = (int*)ws;  ws += ((sizeof(int) * NBKT_A + 15) / 16) * 16;
    char* P = ws;                          // payload union, 25.6 MB
    float2* pxs = (float2*)P;              // [NBKT_S * SLOT_S]  25.6 MB
    float*  pc  = (float*)P;               // [NBKT_A * SLOT_A]  19.2 MB

    // zero both phases' slot counters in one tiny launch
    zero_cnt_kernel<<<1, 1024, 0, stream>>>(gcntS, gcntA);

    // phase 1: v (slot-reserved; no hist/scan launches)
    scatter_bin_sub_kernel<<<NB_SUB, 1024, 0, stream>>>(
        x_met, sto_sub, met_sub, rxn_sub, gcntS, pxs);
    bucket_msg_kernel<<<NBKT_S, 512, 0, stream>>>(
        pxs, gcntS, W1m, b1m, W2m, b2m, W1r, b1r, W2r, b2r, v);

    // phase 2: dxdt (slot-reserved)
    scatter_bin_kernel<<<NB_ALL, 1024, 0, stream>>>(
        sto_all, v, met_all, rxn_all, gcntA, pc);
    bucket_accum_kernel<<<NBKT_A, 512, 0, stream>>>(pc, gcntA, dxdt);
}

// Round 16
// 220.898 us; speedup vs baseline: 1.0874x; 1.0692x over previous
//
#include <hip/hip_runtime.h>

#define N_MET 100000
#define N_RXN 50000
#define E_SUB 2000000
#define E_ALL 4000000
#define MSG_DIM 16
#define HIDDEN 32

// dxdt-side: buckets of 256 mets, 8192-edge tiles, SLOT-RESERVED float2
// payload {sto(packed met&255), rxn} — v-multiply DEFERRED to accum.
#define NBKT_A 391            // ceil(100000/256)
#define NB_ALL 489            // ceil(4000000/8192)
#define TILE_A 8192
#define SLOT_A 12288          // per-bucket capacity (mean 10230, sigma 101)
// v-side: buckets of 64 rxns, 8192-edge tiles, SLOT-RESERVED float2 payload.
#define NBKT_S 782            // ceil(50000/64)
#define NB_SUB 245            // ceil(2000000/8192)
#define TILE_S 8192
#define SLOT_S 4096           // per-bucket capacity (mean 2557, sigma 51)
#define CHUNK_M 3072          // bucket_msg chunk: covers mean+10sigma in ONE chunk

// HW model (R1-R28): scattered GLOBAL atomics = ~19-20 G ops/s wall.
// R13/R17: per-edge latency-chain designs ~450us. R14/R15: in-LDS counting
// sort + register reduce = proven. R20: device-scope fences poison.
// R21/R23: fragmentation conserved; slot reservation = contiguous both
// sides, no histogram. R25: chunk count barely matters. R26/R27: pair-
// reduce ILP-2 > balanced walk; ILP-4 null. R28 (this round): the last
// lever is LAUNCH OVERLAP — phase-2's sort never needed v (defer multiply
// to accum via {sto,rxn} payload), so both scatters fuse into ONE 734-
// block kernel (same-stream kernels never overlap; fused blocks do).
// ws_size checked; sequential fallback with aliased buffers if short.

__device__ __forceinline__ float fast_tanh(float x) {
    // tanh(x) = 1 - 2/(e^{2x}+1); saturates correctly at +-inf. v_exp+v_rcp.
    const float e = __expf(2.0f * x);
    return 1.0f - 2.0f * __builtin_amdgcn_rcpf(e + 1.0f);
}

__global__ __launch_bounds__(1024) void zero_cnt_kernel(
    int* __restrict__ gs, int* __restrict__ ga)
{
    const int t = threadIdx.x;
    for (int i = t; i < NBKT_S; i += 1024) gs[i] = 0;
    for (int i = t; i < NBKT_A; i += 1024) ga[i] = 0;
}

// ---- fused scatter: blocks < p2base do phase-1, rest do phase-2 -------------
// Both: counting-sort tile in LDS (rank atomic -> single-wave scan -> LDS
// scatter), one global atomicAdd per (block,bucket) reserves slot space,
// runs copy out as quarter-wave coalesced bursts.
__global__ __launch_bounds__(1024) void scatter_kernel(
    const float* __restrict__ x_met, const float* __restrict__ sto_sub,
    const int* __restrict__ met_sub, const int* __restrict__ rxn_sub,
    const float* __restrict__ sto_all, const int* __restrict__ met_all,
    const int* __restrict__ rxn_all,
    int* __restrict__ gcntS, int* __restrict__ gcntA,
    float2* __restrict__ pxs, float2* __restrict__ pcx, int p2base)
{
    __shared__ float2 se[8192];          // 64 KB sort buffer (both phases)
    __shared__ int cnt[NBKT_S];
    __shared__ int loff[NBKT_S + 1];
    __shared__ int roff[NBKT_S];
    const int t = threadIdx.x, bk0 = blockIdx.x;

    if (bk0 < p2base) {
        // ================= phase 1: sort by rxn-bucket =================
        const int bk = bk0;
        for (int i = t; i < NBKT_S; i += 1024) cnt[i] = 0;
        __syncthreads();

        const int e0 = bk * TILE_S;
        const int rem = min(TILE_S, E_SUB - e0);
        const int tb = 8 * t;
        float2 pay[8]; int meta[8];
        if (tb + 8 <= rem) {
            const int4 r01 = ((const int4*)(rxn_sub + e0))[2 * t];
            const int4 r23 = ((const int4*)(rxn_sub + e0))[2 * t + 1];
            const int4 m01 = ((const int4*)(met_sub + e0))[2 * t];
            const int4 m23 = ((const int4*)(met_sub + e0))[2 * t + 1];
            const float4 s01 = ((const float4*)(sto_sub + e0))[2 * t];
            const float4 s23 = ((const float4*)(sto_sub + e0))[2 * t + 1];
            const int rr[8] = {r01.x, r01.y, r01.z, r01.w, r23.x, r23.y, r23.z, r23.w};
            const int mm[8] = {m01.x, m01.y, m01.z, m01.w, m23.x, m23.y, m23.z, m23.w};
            const float ss[8] = {s01.x, s01.y, s01.z, s01.w, s23.x, s23.y, s23.z, s23.w};
#pragma unroll
            for (int k = 0; k < 8; ++k) {
                const int r = rr[k];
                const float x = x_met[mm[k]];
                const int sb = (__float_as_int(ss[k]) & ~63) | (r & 63);
                pay[k] = make_float2(x, __int_as_float(sb));
                const int q = r >> 6;
                meta[k] = (atomicAdd(&cnt[q], 1) << 10) | q;   // rank 13b | q 10b
            }
        } else {
#pragma unroll
            for (int k = 0; k < 8; ++k) {
                const int e = e0 + tb + k;
                if (e < E_SUB) {
                    const int r = rxn_sub[e];
                    const float x = x_met[met_sub[e]];
                    const int sb = (__float_as_int(sto_sub[e]) & ~63) | (r & 63);
                    pay[k] = make_float2(x, __int_as_float(sb));
                    const int q = r >> 6;
                    meta[k] = (atomicAdd(&cnt[q], 1) << 10) | q;
                } else meta[k] = -1;
            }
        }
        __syncthreads();

        if (t < 64) {                         // scan cnt[782]
            int carry = 0;
            for (int bb = 0; bb < NBKT_S; bb += 64) {
                const int idx = bb + t;
                const int val = (idx < NBKT_S) ? cnt[idx] : 0;
                int x = val;
#pragma unroll
                for (int off = 1; off < 64; off <<= 1) {
                    const int y = __shfl_up(x, off);
                    if (t >= off) x += y;
                }
                if (idx < NBKT_S) loff[idx] = carry + x - val;
                carry += __shfl(x, 63);
            }
            if (t == 0) loff[NBKT_S] = carry;
        }
        __syncthreads();

#pragma unroll
        for (int k = 0; k < 8; ++k) {
            if (meta[k] >= 0)
                se[loff[meta[k] & 1023] + (meta[k] >> 10)] = pay[k];
        }
        for (int q = t; q < NBKT_S; q += 1024) {
            const int len = loff[q + 1] - loff[q];
            roff[q] = len ? atomicAdd(&gcntS[q], len) : 0;
        }
        __syncthreads();

        const int qw = t >> 4, ql = t & 15;
        for (int q = qw; q < NBKT_S; q += 64) {
            const int s = loff[q], len = loff[q + 1] - s;
            float2* d = pxs + (size_t)q * SLOT_S + roff[q];
            for (int i = ql; i < len; i += 16)
                d[i] = se[s + i];
        }
    } else {
        // ================= phase 2: sort by met-bucket =================
        const int bk = bk0 - p2base;
        for (int i = t; i < NBKT_A; i += 1024) cnt[i] = 0;
        __syncthreads();

        const int e0 = bk * TILE_A;
        const int rem = min(TILE_A, E_ALL - e0);
        const int tb = 8 * t;
        float2 pay[8]; int meta[8];
        if (tb + 8 <= rem) {
            const int4 m01 = ((const int4*)(met_all + e0))[2 * t];
            const int4 m23 = ((const int4*)(met_all + e0))[2 * t + 1];
            const int4 r01 = ((const int4*)(rxn_all + e0))[2 * t];
            const int4 r23 = ((const int4*)(rxn_all + e0))[2 * t + 1];
            const float4 s01 = ((const float4*)(sto_all + e0))[2 * t];
            const float4 s23 = ((const float4*)(sto_all + e0))[2 * t + 1];
            const int mm[8] = {m01.x, m01.y, m01.z, m01.w, m23.x, m23.y, m23.z, m23.w};
            const int rr[8] = {r01.x, r01.y, r01.z, r01.w, r23.x, r23.y, r23.z, r23.w};
            const float ss[8] = {s01.x, s01.y, s01.z, s01.w, s23.x, s23.y, s23.z, s23.w};
#pragma unroll
            for (int k = 0; k < 8; ++k) {
                const int m = mm[k];
                const int sb = (__float_as_int(ss[k]) & ~255) | (m & 255);
                pay[k] = make_float2(__int_as_float(sb), __int_as_float(rr[k]));
                const int q = m >> 8;
                meta[k] = (atomicAdd(&cnt[q], 1) << 9) | q;    // rank 13b | q 9b
            }
        } else {
#pragma unroll
            for (int k = 0; k < 8; ++k) {
                const int e = e0 + tb + k;
                if (e < E_ALL) {
                    const int m = met_all[e];
                    const int sb = (__float_as_int(sto_all[e]) & ~255) | (m & 255);
                    pay[k] = make_float2(__int_as_float(sb),
                                         __int_as_float(rxn_all[e]));
                    const int q = m >> 8;
                    meta[k] = (atomicAdd(&cnt[q], 1) << 9) | q;
                } else meta[k] = -1;
            }
        }
        __syncthreads();

        if (t < 64) {                         // scan cnt[391]
            int carry = 0;
            for (int bb = 0; bb < NBKT_A; bb += 64) {
                const int idx = bb + t;
                const int val = (idx < NBKT_A) ? cnt[idx] : 0;
                int x = val;
#pragma unroll
                for (int off = 1; off < 64; off <<= 1) {
                    const int y = __shfl_up(x, off);
                    if (t >= off) x += y;
                }
                if (idx < NBKT_A) loff[idx] = carry + x - val;
                carry += __shfl(x, 63);
            }
            if (t == 0) loff[NBKT_A] = carry;
        }
        __syncthreads();

#pragma unroll
        for (int k = 0; k < 8; ++k) {
            if (meta[k] >= 0)
                se[loff[meta[k] & 511] + (meta[k] >> 9)] = pay[k];
        }
        for (int q = t; q < NBKT_A; q += 1024) {
            const int len = loff[q + 1] - loff[q];
            roff[q] = len ? atomicAdd(&gcntA[q], len) : 0;
        }
        __syncthreads();

        const int qw = t >> 4, ql = t & 15;
        for (int q = qw; q < NBKT_A; q += 64) {
            const int s = loff[q], len = loff[q + 1] - s;
            float2* d = pcx + (size_t)q * SLOT_A + roff[q];
            for (int i = ql; i < len; i += 16)
                d[i] = se[s + i];
        }
    }
}

// one block (512 thr, 8 waves) per bucket of 64 reactions. R13-proven:
// single-chunk single-round (38.4KB LDS, 4 blk/CU), counting-sort by rxn,
// pair-reduce ILP-2, W2m folded into per-rxn epilogue (linearity).
__global__ __launch_bounds__(512, 8) void bucket_msg_kernel(
    const float2* __restrict__ pxs, const int* __restrict__ gcnt,
    const float* __restrict__ W1m, const float* __restrict__ b1m,
    const float* __restrict__ W2m, const float* __restrict__ b2m,
    const float* __restrict__ W1r, const float* __restrict__ b1r,
    const float* __restrict__ W2r, const float* __restrict__ b2r,
    float* __restrict__ v)
{
    __shared__ float2 se[CHUNK_M];           // edges (24 KB); epilogue sh aliases
    __shared__ float  sth[64 * 33];          // tanh sums [rxn][j], stride 33
    __shared__ int    cnt[64];
    __shared__ int    soff[65];
    __shared__ int    ccnt[64];
    __shared__ float  sW2m[HIDDEN * MSG_DIM];
    __shared__ float  sb2m[MSG_DIM];
    __shared__ float  sW1r[MSG_DIM * HIDDEN];
    __shared__ float  sb1r[HIDDEN];
    __shared__ float  sW2r[HIDDEN];
    __shared__ float  sb2r;
    float* const sh = (float*)se;            // h[64][17], aliases dead se

    const int t = threadIdx.x;
    const int w = t >> 6, l = t & 63;
    const int half = l >> 5, j = l & 31;

    for (int i = t; i < HIDDEN * MSG_DIM; i += 512) sW2m[i] = W2m[i];
    for (int i = t; i < MSG_DIM * HIDDEN; i += 512) sW1r[i] = W1r[i];
    if (t < MSG_DIM) sb2m[t] = b2m[t];
    if (t < HIDDEN) sb1r[t] = b1r[t];
    if (t >= 64 && t < 64 + HIDDEN) sW2r[t - 64] = W2r[t - 64];
    if (t == 128) sb2r = b2r[0];
    if (t < 64) ccnt[t] = 0;

    const float w1x = W1m[j];
    const float w1y = W1m[HIDDEN + j];
    const float w1b = b1m[j];

    const int b = blockIdx.x;
    const int beg = b * SLOT_S;
    const int end = beg + gcnt[b];

    float acc[4] = {0.0f, 0.0f, 0.0f, 0.0f};

    for (int cb = beg; cb < end; cb += CHUNK_M) {
        const int clen = min(end - cb, CHUNK_M);
        if (t < 64) cnt[t] = 0;
        __syncthreads();

        float2 pay[6];
        int meta[6];
#pragma unroll
        for (int k = 0; k < 6; ++k) {
            const int sl = t + (k << 9);
            if (sl < clen) {
                const float2 pv = pxs[cb + sl];
                const int r = __float_as_int(pv.y) & 63;
                meta[k] = (atomicAdd(&cnt[r], 1) << 6) | r;
                pay[k] = pv;
            } else meta[k] = -1;
        }
        __syncthreads();

        if (t < 64) {
            const int orig = cnt[t];
            int x = orig;
#pragma unroll
            for (int off = 1; off < 64; off <<= 1) {
                const int y = __shfl_up(x, off);
                if (t >= off) x += y;
            }
            soff[t] = x - orig;
            if (t == 63) soff[64] = x;
            ccnt[t] += orig;
        }
        __syncthreads();

#pragma unroll
        for (int k = 0; k < 6; ++k) {
            if (meta[k] >= 0)
                se[soff[meta[k] & 63] + (meta[k] >> 6)] = pay[k];
        }
        __syncthreads();

#pragma unroll
        for (int p = 0; p < 4; ++p) {
            const int q = (w << 3) + (p << 1) + half;
            const int rb = soff[q];
            const int rl = soff[q + 1] - rb;
            float a0 = 0.0f, a1 = 0.0f;
            int i = 0;
            for (; i + 2 <= rl; i += 2) {
                const float2 e0 = se[rb + i];
                const float2 e1 = se[rb + i + 1];
                a0 += fast_tanh(fmaf(e0.x, w1x, fmaf(e0.y, w1y, w1b)));
                a1 += fast_tanh(fmaf(e1.x, w1x, fmaf(e1.y, w1y, w1b)));
            }
            if (i < rl) {
                const float2 e0 = se[rb + i];
                a0 += fast_tanh(fmaf(e0.x, w1x, fmaf(e0.y, w1y, w1b)));
            }
            acc[p] += a0 + a1;
        }
        __syncthreads();
    }

#pragma unroll
    for (int p = 0; p < 4; ++p) {
        const int q = (w << 3) + (p << 1) + half;
        sth[q * 33 + j] = acc[p];
    }
    __syncthreads();

    {
        const int r = t & 63, g = (t >> 6) << 1;
        const float cntf = (float)ccnt[r];
        float h0 = cntf * sb2m[g + 0], h1 = cntf * sb2m[g + 1];
#pragma unroll 8
        for (int jj = 0; jj < HIDDEN; ++jj) {
            const float ts = sth[r * 33 + jj];
            h0 = fmaf(ts, sW2m[jj * MSG_DIM + g + 0], h0);
            h1 = fmaf(ts, sW2m[jj * MSG_DIM + g + 1], h1);
        }
        sh[r * 17 + g + 0] = h0;
        sh[r * 17 + g + 1] = h1;
    }
    __syncthreads();

    if (t < 64) {
        const int r = b * 64 + t;
        if (r < N_RXN) {
            float h[MSG_DIM];
#pragma unroll
            for (int d = 0; d < MSG_DIM; ++d) h[d] = sh[t * 17 + d];
            float acc2 = sb2r;
#pragma unroll 2
            for (int jj = 0; jj < HIDDEN; ++jj) {
                float z = sb1r[jj];
#pragma unroll
                for (int d = 0; d < MSG_DIM; ++d)
                    z = fmaf(h[d], sW1r[d * HIDDEN + jj], z);
                acc2 = fmaf(fast_tanh(z), sW2r[jj], acc2);
            }
            v[r] = fmaxf(acc2, 0.0f) + log1pf(expf(-fabsf(acc2)));
        }
    }
}

// block = bucket q (391 blocks): dense float4 slot read (2 edges/load),
// v gathered from L2-hot 200KB array, LDS atomic accumulate, write dxdt.
__global__ __launch_bounds__(512) void bucket_accum_kernel(
    const float2* __restrict__ pcx, const int* __restrict__ gcntA,
    const float* __restrict__ v, float* __restrict__ dxdt)
{
    __shared__ float acc[256];
    const int q = blockIdx.x, t = threadIdx.x;
    if (t < 256) acc[t] = 0.0f;
    __syncthreads();
    const float2* s = pcx + (size_t)q * SLOT_A;   // 16B-aligned
    const int n = gcntA[q];
    const int n2 = n & ~1;
    for (int i = 2 * t; i < n2; i += 1024) {
        const float4 pv = *(const float4*)(s + i);
        const float c0 = pv.x * v[__float_as_int(pv.y)];
        const float c1 = pv.z * v[__float_as_int(pv.w)];
        atomicAdd(&acc[__float_as_int(pv.x) & 255], c0);
        atomicAdd(&acc[__float_as_int(pv.z) & 255], c1);
    }
    for (int i = n2 + t; i < n; i += 512) {
        const float2 p = s[i];
        atomicAdd(&acc[__float_as_int(p.x) & 255],
                  p.x * v[__float_as_int(p.y)]);
    }
    __syncthreads();
    if (t < 256) {
        const int met = q * 256 + t;
        if (met < N_MET) dxdt[met] = acc[t];
    }
}

extern "C" void kernel_launch(void* const* d_in, const int* in_sizes, int n_in,
                              void* d_out, int out_size, void* d_ws, size_t ws_size,
                              hipStream_t stream) {
    const float* x_met   = (const float*)d_in[0];
    const float* sto_sub = (const float*)d_in[1];
    const float* sto_all = (const float*)d_in[2];
    const float* W1m     = (const float*)d_in[3];
    const float* b1m     = (const float*)d_in[4];
    const float* W2m     = (const float*)d_in[5];
    const float* b2m     = (const float*)d_in[6];
    const float* W1r     = (const float*)d_in[7];
    const float* b1r     = (const float*)d_in[8];
    const float* W2r     = (const float*)d_in[9];
    const float* b2r     = (const float*)d_in[10];
    const int*   met_sub = (const int*)d_in[11];
    const int*   rxn_sub = (const int*)d_in[12];
    const int*   met_all = (const int*)d_in[13];
    const int*   rxn_all = (const int*)d_in[14];

    float* dxdt = (float*)d_out;             // [N_MET]
    float* v    = dxdt + N_MET;              // [N_RXN]

    const size_t PXS_B = (size_t)NBKT_S * SLOT_S * sizeof(float2);  // 25.6 MB
    const size_t PCX_B = (size_t)NBKT_A * SLOT_A * sizeof(float2);  // 38.4 MB

    char* ws = (char*)d_ws;
    int* gcntS  = (int*)ws;  ws += ((sizeof(int) * NBKT_S + 15) / 16) * 16;
    int* gcntA  = (int*)ws;  ws += ((sizeof(int) * NBKT_A + 15) / 16) * 16;
    const size_t head = (size_t)(ws - (char*)d_ws);

    zero_cnt_kernel<<<1, 1024, 0, stream>>>(gcntS, gcntA);

    if (ws_size >= head + PXS_B + PCX_B) {
        // parallel path: both scatters fused in ONE kernel (blocks overlap)
        float2* pxs = (float2*)ws;
        float2* pcx = (float2*)(ws + PXS_B);
        scatter_kernel<<<NB_SUB + NB_ALL, 1024, 0, stream>>>(
            x_met, sto_sub, met_sub, rxn_sub, sto_all, met_all, rxn_all,
            gcntS, gcntA, pxs, pcx, NB_SUB);
        bucket_msg_kernel<<<NBKT_S, 512, 0, stream>>>(
            pxs, gcntS, W1m, b1m, W2m, b2m, W1r, b1r, W2r, b2r, v);
        bucket_accum_kernel<<<NBKT_A, 512, 0, stream>>>(pcx, gcntA, v, dxdt);
    } else {
        // sequential fallback: pcx aliases pxs (dead after bucket_msg)
        float2* pxs = (float2*)ws;
        float2* pcx = (float2*)ws;
        scatter_kernel<<<NB_SUB, 1024, 0, stream>>>(
            x_met, sto_sub, met_sub, rxn_sub, sto_all, met_all, rxn_all,
            gcntS, gcntA, pxs, pcx, NB_SUB);
        bucket_msg_kernel<<<NBKT_S, 512, 0, stream>>>(
            pxs, gcntS, W1m, b1m, W2m, b2m, W1r, b1r, W2r, b2r, v);
        scatter_kernel<<<NB_ALL, 1024, 0, stream>>>(
            x_met, sto_sub, met_sub, rxn_sub, sto_all, met_all, rxn_all,
            gcntS, gcntA, pxs, pcx, 0);
        bucket_accum_kernel<<<NBKT_A, 512, 0, stream>>>(pcx, gcntA, v, dxdt);
    }
}